// Round 10
// baseline (360.744 us; speedup 1.0000x reference)
//
#include <hip/hip_runtime.h>

#define N_NODES 100000
#define N_EDGES 1600000
#define NQUAD (N_EDGES / 4)      // 400000
#define NEG_SLOPE 0.2f

#define NBKT 512                 // dst buckets
#define BDIV 196                 // nodes per bucket (510*196=99960; bucket 510 has 40)
#define NUSED 511                // populated buckets
#define PB 500                   // partition blocks
#define QPB (NQUAD / PB)         // 800 quads = 3200 edges per partition block
#define PBS 512                  // histT row stride (pad 500->512)
#define NP2 (N_NODES / PB)       // 200 nodes per part block
#define LT 1024                  // layer-kernel block size (16 waves)

typedef int   vint4   __attribute__((ext_vector_type(4)));
typedef int   vint2   __attribute__((ext_vector_type(2)));
typedef float vfloat4 __attribute__((ext_vector_type(4)));

__device__ __forceinline__ float leaky(float v) { return v >= 0.f ? v : NEG_SLOPE * v; }

// ---------- P0: per-block bucket histogram ----------
__global__ void __launch_bounds__(256) k_hist(const int* __restrict__ ei,
                                              int* __restrict__ histT) {
    __shared__ int hist[NBKT];
    int tid = threadIdx.x;
    hist[tid] = 0;
    hist[tid + 256] = 0;
    __syncthreads();
    const vint4* dst4 = (const vint4*)(ei + N_EDGES);
    int q0 = blockIdx.x * QPB;
    for (int q = tid; q < QPB; q += 256) {
        vint4 d = __builtin_nontemporal_load(&dst4[q0 + q]);
        atomicAdd(&hist[d.x / BDIV], 1);
        atomicAdd(&hist[d.y / BDIV], 1);
        atomicAdd(&hist[d.z / BDIV], 1);
        atomicAdd(&hist[d.w / BDIV], 1);
    }
    __syncthreads();
    histT[tid * PBS + blockIdx.x] = hist[tid];
    histT[(tid + 256) * PBS + blockIdx.x] = hist[tid + 256];
}

// ---------- P1: scan 512x500 table -> exact offsets; fused attention consts ----------
// consts[0..7] cS1[r][h]; [8..15] cD1[r][h]; [16..19] cE1[h]
__global__ void __launch_bounds__(1024) k_scan(const int* __restrict__ histT,
                                               int* __restrict__ offT,
                                               int* __restrict__ bbase,
                                               int* __restrict__ bcnt,
                                               const float* __restrict__ W1,
                                               const float* __restrict__ attS1,
                                               const float* __restrict__ attD1,
                                               const float* __restrict__ We1,
                                               const float* __restrict__ attE1,
                                               float* __restrict__ consts) {
    __shared__ int psum[1024];
    __shared__ int btot[NBKT];
    int tid = threadIdx.x;
    if (tid < 8) {
        int r = tid >> 2, h = tid & 3;
        float s = 0.f;
        for (int c = 0; c < 32; ++c) s += W1[r * 128 + h * 32 + c] * attS1[h * 32 + c];
        consts[tid] = s;
    } else if (tid < 16) {
        int u = tid - 8, r = u >> 2, h = u & 3;
        float s = 0.f;
        for (int c = 0; c < 32; ++c) s += W1[r * 128 + h * 32 + c] * attD1[h * 32 + c];
        consts[tid] = s;
    } else if (tid < 20) {
        int h = tid - 16;
        float s = 0.f;
        for (int c = 0; c < 32; ++c) s += We1[h * 32 + c] * attE1[h * 32 + c];
        consts[tid] = s;
    }
    int b = tid >> 1, q = tid & 1;
    int s = 0;
    for (int k = 0; k < PB / 2; ++k) s += histT[b * PBS + q * (PB / 2) + k];
    psum[tid] = s;
    __syncthreads();
    int mytot = 0;
    if (tid < NBKT) {
        mytot = psum[2 * tid] + psum[2 * tid + 1];
        btot[tid] = mytot;
    }
    __syncthreads();
    for (int off = 1; off < NBKT; off <<= 1) {
        int t = (tid < NBKT && tid >= off) ? btot[tid - off] : 0;
        __syncthreads();
        if (tid < NBKT) btot[tid] += t;
        __syncthreads();
    }
    if (tid < NBKT) {
        int excl = btot[tid] - mytot;
        bbase[tid] = excl;
        bcnt[tid] = mytot;
        btot[tid] = excl;
    }
    __syncthreads();
    int run = btot[b] + (q ? psum[2 * b] : 0);
    for (int k = 0; k < PB / 2; ++k) {
        int pb = q * (PB / 2) + k;
        int c = histT[b * PBS + pb];
        offT[pb * NBKT + b] = run;
        run += c;
    }
}

// ---------- P2: partition edges to bucket-grouped staging + fused node records ----------
// Each (block,bucket) staging segment is single-writer & contiguous -> writes
// combine in this CU's L2 regardless of XCD placement.
__global__ void __launch_bounds__(512) k_part(const int* __restrict__ ei,
                                              const float* __restrict__ w,
                                              const int* __restrict__ offT,
                                              const float* __restrict__ x,
                                              const float* __restrict__ consts,
                                              int2* __restrict__ staging,
                                              float* __restrict__ nodeRec,
                                              float* __restrict__ aD1) {
    __shared__ int lcur[NBKT];
    int tid = threadIdx.x;
    if (tid < NBKT) lcur[tid] = offT[blockIdx.x * NBKT + tid];
    __syncthreads();
    const vint4* src4 = (const vint4*)ei;
    const vint4* dst4 = (const vint4*)(ei + N_EDGES);
    const vfloat4* w4 = (const vfloat4*)w;
    int q0 = blockIdx.x * QPB;
    for (int q = tid; q < QPB; q += 512) {
        vint4 s = __builtin_nontemporal_load(&src4[q0 + q]);
        vint4 d = __builtin_nontemporal_load(&dst4[q0 + q]);
        vfloat4 ww = __builtin_nontemporal_load(&w4[q0 + q]);
#pragma unroll
        for (int j = 0; j < 4; ++j) {
            int dd = (j == 0) ? d.x : (j == 1) ? d.y : (j == 2) ? d.z : d.w;
            int ss = (j == 0) ? s.x : (j == 1) ? s.y : (j == 2) ? s.z : s.w;
            float wv = (j == 0) ? ww.x : (j == 1) ? ww.y : (j == 2) ? ww.z : ww.w;
            int b = dd / BDIV;
            int pos = atomicAdd(&lcur[b], 1);
            staging[pos] = make_int2(ss | ((dd - b * BDIV) << 17), __float_as_int(wv));
        }
    }
    for (int j = tid; j < NP2; j += 512) {
        int n = blockIdx.x * NP2 + j;
        float x0 = x[2 * n], x1 = x[2 * n + 1];
#pragma unroll
        for (int h = 0; h < 4; ++h) {
            nodeRec[n * 8 + h] = x0 * consts[h] + x1 * consts[4 + h];
            aD1[n * 4 + h]     = x0 * consts[8 + h] + x1 * consts[12 + h];
        }
        nodeRec[n * 8 + 4] = x0;
        nodeRec[n * 8 + 5] = x1;
        nodeRec[n * 8 + 6] = 0.f;
        nodeRec[n * 8 + 7] = 0.f;
    }
}

// ---------- P3: layer-1 per bucket (1024 thr): LDS-atomic softmax + MLP -> h2, la ----------
__global__ void __launch_bounds__(LT) k_layer1(const int* __restrict__ bbase,
                                               const int* __restrict__ bcnt,
                                               const int2* __restrict__ staging,
                                               const float* __restrict__ nodeRec,
                                               const float* __restrict__ aD1,
                                               const float* __restrict__ consts,
                                               const float* __restrict__ W1,
                                               const float* __restrict__ b1,
                                               const float* __restrict__ W2,
                                               float* __restrict__ h2,
                                               float* __restrict__ la) {
    __shared__ float sA[BDIV * 4], X0A[BDIV * 4], X1A[BDIV * 4], adL[BDIV * 4];
    __shared__ float wsA[BDIV], cA[BDIV];
    __shared__ float w10[132], w11[132], b1s[132], w2s[132];
    int b = blockIdx.x, tid = threadIdx.x;
    int n0 = b * BDIV;
    int nnode = min(BDIV, N_NODES - n0);
    for (int j = tid; j < BDIV * 4; j += LT) {
        sA[j] = 0.f; X0A[j] = 0.f; X1A[j] = 0.f;
        adL[j] = (j < nnode * 4) ? aD1[n0 * 4 + j] : 0.f;
    }
    for (int j = tid; j < BDIV; j += LT) { wsA[j] = 0.f; cA[j] = 0.f; }
    for (int j = tid; j < 128; j += LT) {
        int jj = (j >> 5) * 33 + (j & 31);
        w10[jj] = W1[j]; w11[jj] = W1[128 + j]; b1s[jj] = b1[j]; w2s[jj] = W2[j];
    }
    float cE0 = consts[16], cE1 = consts[17], cE2 = consts[18], cE3 = consts[19];
    __syncthreads();
    int base = bbase[b], cnt = bcnt[b];
    const vint2* st2 = (const vint2*)staging;
    for (int i = base + tid; i < base + cnt; i += LT) {
        vint2 e = st2[i];
        int src = e.x & 0x1FFFF;
        int dl = e.x >> 17;
        float wt = __int_as_float(e.y);
        vfloat4 as = *(const vfloat4*)(nodeRec + src * 8);
        vfloat4 xs = *(const vfloat4*)(nodeRec + src * 8 + 4);
        float p0 = __expf(leaky(as.x + adL[dl * 4 + 0] + wt * cE0));
        float p1 = __expf(leaky(as.y + adL[dl * 4 + 1] + wt * cE1));
        float p2 = __expf(leaky(as.z + adL[dl * 4 + 2] + wt * cE2));
        float p3 = __expf(leaky(as.w + adL[dl * 4 + 3] + wt * cE3));
        atomicAdd(&sA[dl * 4 + 0], p0);  atomicAdd(&sA[dl * 4 + 1], p1);
        atomicAdd(&sA[dl * 4 + 2], p2);  atomicAdd(&sA[dl * 4 + 3], p3);
        atomicAdd(&X0A[dl * 4 + 0], p0 * xs.x);  atomicAdd(&X0A[dl * 4 + 1], p1 * xs.x);
        atomicAdd(&X0A[dl * 4 + 2], p2 * xs.x);  atomicAdd(&X0A[dl * 4 + 3], p3 * xs.x);
        atomicAdd(&X1A[dl * 4 + 0], p0 * xs.y);  atomicAdd(&X1A[dl * 4 + 1], p1 * xs.y);
        atomicAdd(&X1A[dl * 4 + 2], p2 * xs.y);  atomicAdd(&X1A[dl * 4 + 3], p3 * xs.y);
        atomicAdd(&wsA[dl], wt);
        atomicAdd(&cA[dl], 1.f);
    }
    __syncthreads();
    for (int j = tid; j < nnode; j += LT) {
        int n = n0 + j;
        float d = cA[j];
        float lav = wsA[j] / fmaxf(d, 1.f);
        la[n] = lav;
        vfloat4 aso = *(const vfloat4*)(nodeRec + n * 8);
        vfloat4 xo = *(const vfloat4*)(nodeRec + n * 8 + 4);
        float asov[4] = {aso.x, aso.y, aso.z, aso.w};
        float cE[4] = {cE0, cE1, cE2, cE3};
        float acc = 0.f;
#pragma unroll
        for (int h = 0; h < 4; ++h) {
            float p = __expf(leaky(asov[h] + adL[j * 4 + h] + lav * cE[h]));
            float sh = sA[j * 4 + h] + p;
            float inv = 1.f / (sh + 1e-16f);
            float X0h = (X0A[j * 4 + h] + p * xo.x) * inv;
            float X1h = (X1A[j * 4 + h] + p * xo.y) * inv;
            int bj = h * 33;
            for (int c = 0; c < 32; ++c) {
                float v = X0h * w10[bj + c] + X1h * w11[bj + c] + b1s[bj + c];
                float el = v > 0.f ? v : __expf(v) - 1.f;  // elu
                acc += el * w2s[bj + c];
            }
        }
        h2[n] = acc;
    }
}

// ---------- P4: layer-2 per bucket (1024 thr) -> out ----------
__global__ void __launch_bounds__(LT) k_layer2(const int* __restrict__ bbase,
                                               const int* __restrict__ bcnt,
                                               const int2* __restrict__ staging,
                                               const float* __restrict__ h2,
                                               const float* __restrict__ la,
                                               const float* __restrict__ attS2,
                                               const float* __restrict__ attD2,
                                               const float* __restrict__ We2,
                                               const float* __restrict__ attE2,
                                               const float* __restrict__ b2,
                                               float* __restrict__ out) {
    __shared__ float h2L[BDIV], s2A[BDIV], a2A[BDIV];
    int b = blockIdx.x, tid = threadIdx.x;
    int n0 = b * BDIV;
    int nnode = min(BDIV, N_NODES - n0);
    for (int j = tid; j < BDIV; j += LT) {
        h2L[j] = (j < nnode) ? h2[n0 + j] : 0.f;
        s2A[j] = 0.f; a2A[j] = 0.f;
    }
    float aS = attS2[0], aD = attD2[0], cE = We2[0] * attE2[0], bb = b2[0];
    __syncthreads();
    int base = bbase[b], cnt = bcnt[b];
    const vint2* st2 = (const vint2*)staging;
    for (int i = base + tid; i < base + cnt; i += LT) {
        vint2 e = st2[i];
        int src = e.x & 0x1FFFF;
        int dl = e.x >> 17;
        float wt = __int_as_float(e.y);
        float hs = h2[src];
        float p = __expf(leaky(hs * aS + h2L[dl] * aD + wt * cE));
        atomicAdd(&s2A[dl], p);
        atomicAdd(&a2A[dl], p * hs);
    }
    __syncthreads();
    for (int j = tid; j < nnode; j += LT) {
        int n = n0 + j;
        float hn = h2L[j];
        float p = __expf(leaky(hn * aS + hn * aD + la[n] * cE));
        float s = s2A[j] + p;
        float acc = a2A[j] + p * hn;
        out[n] = acc / (s + 1e-16f) + bb;
    }
}

extern "C" void kernel_launch(void* const* d_in, const int* in_sizes, int n_in,
                              void* d_out, int out_size, void* d_ws, size_t ws_size,
                              hipStream_t stream) {
    const float* x     = (const float*)d_in[0];
    const int*   ei    = (const int*)d_in[1];
    const float* w     = (const float*)d_in[2];
    const float* W1    = (const float*)d_in[3];
    const float* attS1 = (const float*)d_in[4];
    const float* attD1 = (const float*)d_in[5];
    const float* We1   = (const float*)d_in[6];
    const float* attE1 = (const float*)d_in[7];
    const float* b1    = (const float*)d_in[8];
    const float* W2    = (const float*)d_in[9];
    const float* attS2 = (const float*)d_in[10];
    const float* attD2 = (const float*)d_in[11];
    const float* We2   = (const float*)d_in[12];
    const float* attE2 = (const float*)d_in[13];
    const float* b2    = (const float*)d_in[14];
    float* out = (float*)d_out;

    const size_t N = N_NODES;

    // workspace layout (~19.5 MB total; no zero-init needed anywhere)
    int*   histT   = (int*)d_ws;                      // NBKT*PBS = 262144
    int*   offT    = histT + NBKT * PBS;              // PB*NBKT  = 256000
    int*   bbase   = offT + PB * NBKT;                // 512
    int*   bcnt    = bbase + NBKT;                    // 512
    float* consts  = (float*)(bcnt + NBKT);           // 32
    int2*  staging = (int2*)(consts + 32);            // E (8B-aligned)
    float* nodeRec = (float*)(staging + N_EDGES);     // 8N (16B-aligned)
    float* aD1     = nodeRec + 8 * N;                 // 4N
    float* h2      = aD1 + 4 * N;                     // N
    float* la      = h2 + N;                          // N

    k_hist<<<PB, 256, 0, stream>>>(ei, histT);
    k_scan<<<1, 1024, 0, stream>>>(histT, offT, bbase, bcnt, W1, attS1, attD1, We1,
                                   attE1, consts);
    k_part<<<PB, 512, 0, stream>>>(ei, w, offT, x, consts, staging, nodeRec, aD1);
    k_layer1<<<NUSED, LT, 0, stream>>>(bbase, bcnt, staging, nodeRec, aD1, consts,
                                       W1, b1, W2, h2, la);
    k_layer2<<<NUSED, LT, 0, stream>>>(bbase, bcnt, staging, h2, la, attS2, attD2,
                                       We2, attE2, b2, out);
}

// Round 11
// 265.709 us; speedup vs baseline: 1.3577x; 1.3577x over previous
//
#include <hip/hip_runtime.h>

#define N_NODES 100000
#define N_EDGES 1600000
#define NQUAD (N_EDGES / 4)      // 400000
#define NEG_SLOPE 0.2f

#define NBKT 512                 // dst buckets (510 populated + tail)
#define BDIV 196                 // nodes per bucket
#define NUSED 511                // bucket blocks launched
#define PB 500                   // partition blocks
#define QPB (NQUAD / PB)         // 800 quads = 3200 edges per partition block
#define PBS 512                  // histT row stride
#define BCAP 4096                // k_build LDS segment cap (mean 3136, +17 sigma)

typedef int   vint4   __attribute__((ext_vector_type(4)));
typedef float vfloat4 __attribute__((ext_vector_type(4)));

__device__ __forceinline__ float leaky(float v) { return v >= 0.f ? v : NEG_SLOPE * v; }

// ---------- P0: per-block bucket histogram ----------
__global__ void __launch_bounds__(256) k_hist(const int* __restrict__ ei,
                                              int* __restrict__ histT) {
    __shared__ int hist[NBKT];
    int tid = threadIdx.x;
    hist[tid] = 0;
    hist[tid + 256] = 0;
    __syncthreads();
    const vint4* dst4 = (const vint4*)(ei + N_EDGES);
    int q0 = blockIdx.x * QPB;
    for (int q = tid; q < QPB; q += 256) {
        vint4 d = __builtin_nontemporal_load(&dst4[q0 + q]);
        atomicAdd(&hist[d.x / BDIV], 1);
        atomicAdd(&hist[d.y / BDIV], 1);
        atomicAdd(&hist[d.z / BDIV], 1);
        atomicAdd(&hist[d.w / BDIV], 1);
    }
    __syncthreads();
    histT[tid * PBS + blockIdx.x] = hist[tid];
    histT[(tid + 256) * PBS + blockIdx.x] = hist[tid + 256];
}

// ---------- P1: scan 512x500 table -> exact offsets; fused attention consts ----------
// consts[0..7] cS1[r][h]; [8..15] cD1[r][h]; [16..19] cE1[h]
__global__ void __launch_bounds__(1024) k_scan(const int* __restrict__ histT,
                                               int* __restrict__ offT,
                                               int* __restrict__ bbase,
                                               int* __restrict__ bcnt,
                                               const float* __restrict__ W1,
                                               const float* __restrict__ attS1,
                                               const float* __restrict__ attD1,
                                               const float* __restrict__ We1,
                                               const float* __restrict__ attE1,
                                               float* __restrict__ consts) {
    __shared__ int psum[1024];
    __shared__ int btot[NBKT];
    int tid = threadIdx.x;
    if (tid < 8) {
        int r = tid >> 2, h = tid & 3;
        float s = 0.f;
        for (int c = 0; c < 32; ++c) s += W1[r * 128 + h * 32 + c] * attS1[h * 32 + c];
        consts[tid] = s;
    } else if (tid < 16) {
        int u = tid - 8, r = u >> 2, h = u & 3;
        float s = 0.f;
        for (int c = 0; c < 32; ++c) s += W1[r * 128 + h * 32 + c] * attD1[h * 32 + c];
        consts[tid] = s;
    } else if (tid < 20) {
        int h = tid - 16;
        float s = 0.f;
        for (int c = 0; c < 32; ++c) s += We1[h * 32 + c] * attE1[h * 32 + c];
        consts[tid] = s;
    }
    int b = tid >> 1, q = tid & 1;
    int s = 0;
    for (int k = 0; k < PB / 2; ++k) s += histT[b * PBS + q * (PB / 2) + k];
    psum[tid] = s;
    __syncthreads();
    int mytot = 0;
    if (tid < NBKT) {
        mytot = psum[2 * tid] + psum[2 * tid + 1];
        btot[tid] = mytot;
    }
    __syncthreads();
    for (int off = 1; off < NBKT; off <<= 1) {
        int t = (tid < NBKT && tid >= off) ? btot[tid - off] : 0;
        __syncthreads();
        if (tid < NBKT) btot[tid] += t;
        __syncthreads();
    }
    if (tid < NBKT) {
        int excl = btot[tid] - mytot;
        bbase[tid] = excl;
        bcnt[tid] = mytot;
        btot[tid] = excl;
    }
    __syncthreads();
    int run = btot[b] + (q ? psum[2 * b] : 0);
    for (int k = 0; k < PB / 2; ++k) {
        int pb = q * (PB / 2) + k;
        int c = histT[b * PBS + pb];
        offT[pb * NBKT + b] = run;
        run += c;
    }
}

// ---------- P2: partition edges to 16B payload records, bucket-grouped ----------
// record = {src | dl<<17, w, x0[src], x1[src]} so downstream never random-reads.
// Each (block,bucket) segment is single-writer & contiguous -> L2 write-combining.
__global__ void __launch_bounds__(512) k_part(const int* __restrict__ ei,
                                              const float* __restrict__ w,
                                              const int* __restrict__ offT,
                                              const float* __restrict__ x,
                                              vint4* __restrict__ staging) {
    __shared__ int lcur[NBKT];
    int tid = threadIdx.x;
    lcur[tid] = offT[blockIdx.x * NBKT + tid];
    lcur[tid + 256] = offT[blockIdx.x * NBKT + tid + 256];
    __syncthreads();
    const vint4* src4 = (const vint4*)ei;
    const vint4* dst4 = (const vint4*)(ei + N_EDGES);
    const vfloat4* w4 = (const vfloat4*)w;
    int q0 = blockIdx.x * QPB;
    for (int q = tid; q < QPB; q += 512) {
        vint4 s = __builtin_nontemporal_load(&src4[q0 + q]);
        vint4 d = __builtin_nontemporal_load(&dst4[q0 + q]);
        vfloat4 ww = __builtin_nontemporal_load(&w4[q0 + q]);
#pragma unroll
        for (int j = 0; j < 4; ++j) {
            int dd = (j == 0) ? d.x : (j == 1) ? d.y : (j == 2) ? d.z : d.w;
            int ss = (j == 0) ? s.x : (j == 1) ? s.y : (j == 2) ? s.z : s.w;
            float wv = (j == 0) ? ww.x : (j == 1) ? ww.y : (j == 2) ? ww.z : ww.w;
            int b = dd / BDIV;
            int pos = atomicAdd(&lcur[b], 1);
            float2 xs = *(const float2*)(x + 2 * ss);
            vint4 r = {ss | ((dd - b * BDIV) << 17), __float_as_int(wv),
                       __float_as_int(xs.x), __float_as_int(xs.y)};
            staging[pos] = r;
        }
    }
}

// ---------- P3: per-bucket CSR finish, in-place via LDS segment buffer ----------
// Local int hist + scan -> deg/rowst; place records in row order. All global
// writes land in this CU's hot 64KB segment -> L2-local.
__global__ void __launch_bounds__(512) k_build(const int* __restrict__ bbase,
                                               const int* __restrict__ bcnt,
                                               vint4* __restrict__ staging,
                                               int* __restrict__ deg,
                                               int* __restrict__ rowst) {
    __shared__ vint4 seg[BCAP];       // 64 KB
    __shared__ int hist[256];
    __shared__ int lcur[BDIV];
    int b = blockIdx.x, tid = threadIdx.x;
    int base = bbase[b];
    int cnt = min(bcnt[b], BCAP);     // clamp is memory-safety only; never hit
    if (tid < 256) hist[tid] = 0;
    __syncthreads();
    for (int i = tid; i < cnt; i += 512) {
        vint4 r = staging[base + i];
        seg[i] = r;
        atomicAdd(&hist[r.x >> 17], 1);
    }
    __syncthreads();
    int v = (tid < 256) ? hist[tid] : 0;
    for (int off = 1; off < 256; off <<= 1) {   // inclusive scan (first 256 thr)
        int t = (tid < 256 && tid >= off) ? hist[tid - off] : 0;
        __syncthreads();
        if (tid < 256) hist[tid] += t;
        __syncthreads();
    }
    int n0 = b * BDIV;
    int nnode = min(BDIV, N_NODES - n0);
    if (tid < nnode) {
        deg[n0 + tid] = v;
        rowst[n0 + tid] = base + hist[tid] - v;
    }
    if (tid < BDIV) lcur[tid] = hist[tid] - v;  // exclusive prefix
    __syncthreads();
    for (int i = tid; i < cnt; i += 512) {
        vint4 r = seg[i];
        int pos = atomicAdd(&lcur[r.x >> 17], 1);
        staging[base + pos] = r;
    }
}

// ---------- P4: layer-1 gather, 8 lanes/node, zero random reads, fused MLP ----------
__global__ void __launch_bounds__(256) k_gather1(const int* __restrict__ deg,
                                                 const int* __restrict__ rowst,
                                                 const vint4* __restrict__ csr,
                                                 const float* __restrict__ x,
                                                 const float* __restrict__ consts,
                                                 const float* __restrict__ W1,
                                                 const float* __restrict__ b1,
                                                 const float* __restrict__ W2,
                                                 float* __restrict__ h2,
                                                 float* __restrict__ la) {
    __shared__ float w10[132], w11[132], b1s[132], w2s[132];  // stride-33 pad
    for (int j = threadIdx.x; j < 128; j += blockDim.x) {
        int jj = (j >> 5) * 33 + (j & 31);
        w10[jj] = W1[j];
        w11[jj] = W1[128 + j];
        b1s[jj] = b1[j];
        w2s[jj] = W2[j];
    }
    __syncthreads();
    int t = blockIdx.x * blockDim.x + threadIdx.x;
    int n = t >> 3, l = t & 7;
    if (n >= N_NODES) return;
    float c[20];
#pragma unroll
    for (int i = 0; i < 20; ++i) c[i] = consts[i];
    int rs = rowst[n], d = deg[n];
    float2 xn = *(const float2*)(x + 2 * n);
    float adv[4];
#pragma unroll
    for (int h = 0; h < 4; ++h) adv[h] = xn.x * c[8 + h] + xn.y * c[12 + h];
    float s[4] = {0, 0, 0, 0}, X0[4] = {0, 0, 0, 0}, X1[4] = {0, 0, 0, 0};
    float wsum = 0.f;
    for (int k = rs + l; k < rs + d; k += 8) {
        vint4 r = csr[k];
        float wt = __int_as_float(r.y);
        float x0s = __int_as_float(r.z), x1s = __int_as_float(r.w);
        wsum += wt;
#pragma unroll
        for (int h = 0; h < 4; ++h) {
            float as = x0s * c[h] + x1s * c[4 + h];
            float p = __expf(leaky(as + adv[h] + wt * c[16 + h]));
            s[h] += p;
            X0[h] += p * x0s;
            X1[h] += p * x1s;
        }
    }
#pragma unroll
    for (int off = 1; off < 8; off <<= 1) {
        wsum += __shfl_xor(wsum, off);
#pragma unroll
        for (int h = 0; h < 4; ++h) {
            s[h]  += __shfl_xor(s[h], off);
            X0[h] += __shfl_xor(X0[h], off);
            X1[h] += __shfl_xor(X1[h], off);
        }
    }
    // self loop (redundant on all 8 lanes): edge attr = mean incident weight
    float lav = wsum / fmaxf((float)d, 1.f);
#pragma unroll
    for (int h = 0; h < 4; ++h) {
        float aso = xn.x * c[h] + xn.y * c[4 + h];
        float p = __expf(leaky(aso + adv[h] + lav * c[16 + h]));
        s[h] += p;
        X0[h] += p * xn.x;
        X1[h] += p * xn.y;
    }
    // MLP tail: lane l -> head l&3, channel-half l>>2 (16 ch each)
    int hh = l & 3;
    float sh  = (hh == 0) ? s[0]  : (hh == 1) ? s[1]  : (hh == 2) ? s[2]  : s[3];
    float X0h = (hh == 0) ? X0[0] : (hh == 1) ? X0[1] : (hh == 2) ? X0[2] : X0[3];
    float X1h = (hh == 0) ? X1[0] : (hh == 1) ? X1[1] : (hh == 2) ? X1[2] : X1[3];
    float inv = 1.f / (sh + 1e-16f);
    X0h *= inv;
    X1h *= inv;
    float acc = 0.f;
    int basej = hh * 33 + (l >> 2) * 16;
    for (int cc = 0; cc < 16; ++cc) {
        float v = X0h * w10[basej + cc] + X1h * w11[basej + cc] + b1s[basej + cc];
        float el = v > 0.f ? v : __expf(v) - 1.f;  // elu
        acc += el * w2s[basej + cc];
    }
    acc += __shfl_xor(acc, 1);
    acc += __shfl_xor(acc, 2);
    acc += __shfl_xor(acc, 4);
    if (l == 0) {
        h2[n] = acc;
        la[n] = lav;
    }
}

// ---------- P5: layer-2 gather, 8 lanes/node -> out ----------
__global__ void __launch_bounds__(256) k_gather2(const int* __restrict__ deg,
                                                 const int* __restrict__ rowst,
                                                 const vint4* __restrict__ csr,
                                                 const float* __restrict__ h2,
                                                 const float* __restrict__ la,
                                                 const float* __restrict__ attS2,
                                                 const float* __restrict__ attD2,
                                                 const float* __restrict__ We2,
                                                 const float* __restrict__ attE2,
                                                 const float* __restrict__ b2,
                                                 float* __restrict__ out) {
    int t = blockIdx.x * blockDim.x + threadIdx.x;
    int n = t >> 3, l = t & 7;
    if (n >= N_NODES) return;
    float aS = attS2[0], aD = attD2[0], cE = We2[0] * attE2[0], bb = b2[0];
    int rs = rowst[n], d = deg[n];
    float hn = h2[n];
    float hnaD = hn * aD;
    float s = 0.f, acc = 0.f;
    for (int k = rs + l; k < rs + d; k += 8) {
        vint4 r = csr[k];
        float hs = h2[r.x & 0x1FFFF];
        float wt = __int_as_float(r.y);
        float p = __expf(leaky(hs * aS + hnaD + wt * cE));
        s += p;
        acc += p * hs;
    }
#pragma unroll
    for (int off = 1; off < 8; off <<= 1) {
        s   += __shfl_xor(s, off);
        acc += __shfl_xor(acc, off);
    }
    float p = __expf(leaky(hn * aS + hnaD + la[n] * cE));
    s += p;
    acc += p * hn;
    if (l == 0) out[n] = acc / (s + 1e-16f) + bb;
}

extern "C" void kernel_launch(void* const* d_in, const int* in_sizes, int n_in,
                              void* d_out, int out_size, void* d_ws, size_t ws_size,
                              hipStream_t stream) {
    const float* x     = (const float*)d_in[0];
    const int*   ei    = (const int*)d_in[1];
    const float* w     = (const float*)d_in[2];
    const float* W1    = (const float*)d_in[3];
    const float* attS1 = (const float*)d_in[4];
    const float* attD1 = (const float*)d_in[5];
    const float* We1   = (const float*)d_in[6];
    const float* attE1 = (const float*)d_in[7];
    const float* b1    = (const float*)d_in[8];
    const float* W2    = (const float*)d_in[9];
    const float* attS2 = (const float*)d_in[10];
    const float* attD2 = (const float*)d_in[11];
    const float* We2   = (const float*)d_in[12];
    const float* attE2 = (const float*)d_in[13];
    const float* b2    = (const float*)d_in[14];
    float* out = (float*)d_out;

    const size_t N = N_NODES;

    // workspace layout (~29.7 MB; nothing needs zero-init)
    int*   histT   = (int*)d_ws;                      // 512*512 = 262144
    int*   offT    = histT + NBKT * PBS;              // 500*512 = 256000
    int*   bbase   = offT + PB * NBKT;                // 512
    int*   bcnt    = bbase + NBKT;                    // 512
    float* consts  = (float*)(bcnt + NBKT);           // 32
    vint4* staging = (vint4*)(consts + 32);           // E * 16B (16B-aligned)
    int*   deg     = (int*)(staging + N_EDGES);       // N
    int*   rowst   = deg + N;                         // N
    float* h2      = (float*)(rowst + N);             // N
    float* la      = h2 + N;                          // N

    k_hist<<<PB, 256, 0, stream>>>(ei, histT);
    k_scan<<<1, 1024, 0, stream>>>(histT, offT, bbase, bcnt, W1, attS1, attD1, We1,
                                   attE1, consts);
    k_part<<<PB, 512, 0, stream>>>(ei, w, offT, x, staging);
    k_build<<<NUSED, 512, 0, stream>>>(bbase, bcnt, staging, deg, rowst);
    k_gather1<<<(8 * N_NODES + 255) / 256, 256, 0, stream>>>(deg, rowst, staging, x,
                                                             consts, W1, b1, W2, h2, la);
    k_gather2<<<(8 * N_NODES + 255) / 256, 256, 0, stream>>>(deg, rowst, staging, h2, la,
                                                             attS2, attD2, We2, attE2,
                                                             b2, out);
}

// Round 12
// 176.614 us; speedup vs baseline: 2.0426x; 1.5045x over previous
//
#include <hip/hip_runtime.h>

#define N_NODES 100000
#define N_EDGES 1600000
#define NQUAD (N_EDGES / 4)      // 400000
#define NEG_SLOPE 0.2f

#define NBKT 512                 // dst buckets (510 populated + tail)
#define BDIV 196                 // nodes per bucket
#define NUSED 511                // bucket blocks launched
#define PB 500                   // partition blocks
#define QPB (NQUAD / PB)         // 800 quads = 3200 edges per partition block
#define PBS 512                  // histT/offT row stride (bucket-major)
#define BCAP 4096                // k_build LDS segment cap (mean 3136, +17 sigma)

typedef int   vint4   __attribute__((ext_vector_type(4)));
typedef float vfloat4 __attribute__((ext_vector_type(4)));

__device__ __forceinline__ float leaky(float v) { return v >= 0.f ? v : NEG_SLOPE * v; }

// ---------- P0: per-block bucket histogram (bucket-major output) ----------
__global__ void __launch_bounds__(256) k_hist(const int* __restrict__ ei,
                                              int* __restrict__ histT) {
    __shared__ int hist[NBKT];
    int tid = threadIdx.x;
    hist[tid] = 0;
    hist[tid + 256] = 0;
    __syncthreads();
    const vint4* dst4 = (const vint4*)(ei + N_EDGES);
    int q0 = blockIdx.x * QPB;
    for (int q = tid; q < QPB; q += 256) {
        vint4 d = __builtin_nontemporal_load(&dst4[q0 + q]);
        atomicAdd(&hist[d.x / BDIV], 1);
        atomicAdd(&hist[d.y / BDIV], 1);
        atomicAdd(&hist[d.z / BDIV], 1);
        atomicAdd(&hist[d.w / BDIV], 1);
    }
    __syncthreads();
    histT[tid * PBS + blockIdx.x] = hist[tid];
    histT[(tid + 256) * PBS + blockIdx.x] = hist[tid + 256];
}

// ---------- P1a: per-bucket row scan (512 blocks) ----------
// offT[b][pb] = exclusive prefix of histT[b][0..pb-1]; btot[b] = row total.
__global__ void __launch_bounds__(512) k_rowscan(const int* __restrict__ histT,
                                                 int* __restrict__ offT,
                                                 int* __restrict__ btot) {
    __shared__ int sm[512];
    int b = blockIdx.x, tid = threadIdx.x;
    int v = (tid < PB) ? histT[b * PBS + tid] : 0;
    sm[tid] = v;
    __syncthreads();
    for (int off = 1; off < 512; off <<= 1) {
        int t = (tid >= off) ? sm[tid - off] : 0;
        __syncthreads();
        sm[tid] += t;
        __syncthreads();
    }
    if (tid < PB) offT[b * PBS + tid] = sm[tid] - v;   // exclusive, contiguous write
    if (tid == 511) btot[b] = sm[511];
}

// ---------- P1b: bucket-base prefix (1 block) + fused attention consts ----------
// consts[0..7] cS1[r][h]; [8..15] cD1[r][h]; [16..19] cE1[h]
__global__ void __launch_bounds__(512) k_bprefix(const int* __restrict__ btot,
                                                 int* __restrict__ bbase,
                                                 int* __restrict__ bcnt,
                                                 const float* __restrict__ W1,
                                                 const float* __restrict__ attS1,
                                                 const float* __restrict__ attD1,
                                                 const float* __restrict__ We1,
                                                 const float* __restrict__ attE1,
                                                 float* __restrict__ consts) {
    __shared__ int sm[512];
    int tid = threadIdx.x;
    if (tid < 8) {
        int r = tid >> 2, h = tid & 3;
        float s = 0.f;
        for (int c = 0; c < 32; ++c) s += W1[r * 128 + h * 32 + c] * attS1[h * 32 + c];
        consts[tid] = s;
    } else if (tid < 16) {
        int u = tid - 8, r = u >> 2, h = u & 3;
        float s = 0.f;
        for (int c = 0; c < 32; ++c) s += W1[r * 128 + h * 32 + c] * attD1[h * 32 + c];
        consts[tid] = s;
    } else if (tid < 20) {
        int h = tid - 16;
        float s = 0.f;
        for (int c = 0; c < 32; ++c) s += We1[h * 32 + c] * attE1[h * 32 + c];
        consts[tid] = s;
    }
    int v = btot[tid];
    sm[tid] = v;
    __syncthreads();
    for (int off = 1; off < 512; off <<= 1) {
        int t = (tid >= off) ? sm[tid - off] : 0;
        __syncthreads();
        sm[tid] += t;
        __syncthreads();
    }
    bbase[tid] = sm[tid] - v;   // exclusive
    bcnt[tid] = v;
}

// ---------- P2: partition edges to 16B payload records, bucket-grouped ----------
// record = {src | dl<<17, w, x0[src], x1[src]} so downstream never random-reads.
// Each (block,bucket) segment is single-writer & contiguous -> L2 write-combining.
__global__ void __launch_bounds__(512) k_part(const int* __restrict__ ei,
                                              const float* __restrict__ w,
                                              const int* __restrict__ offT,
                                              const int* __restrict__ bbase,
                                              const float* __restrict__ x,
                                              vint4* __restrict__ staging) {
    __shared__ int lcur[NBKT];
    int tid = threadIdx.x;
    lcur[tid] = offT[tid * PBS + blockIdx.x] + bbase[tid];   // one write/thread (512)
    __syncthreads();
    const vint4* src4 = (const vint4*)ei;
    const vint4* dst4 = (const vint4*)(ei + N_EDGES);
    const vfloat4* w4 = (const vfloat4*)w;
    int q0 = blockIdx.x * QPB;
    for (int q = tid; q < QPB; q += 512) {
        vint4 s = __builtin_nontemporal_load(&src4[q0 + q]);
        vint4 d = __builtin_nontemporal_load(&dst4[q0 + q]);
        vfloat4 ww = __builtin_nontemporal_load(&w4[q0 + q]);
#pragma unroll
        for (int j = 0; j < 4; ++j) {
            int dd = (j == 0) ? d.x : (j == 1) ? d.y : (j == 2) ? d.z : d.w;
            int ss = (j == 0) ? s.x : (j == 1) ? s.y : (j == 2) ? s.z : s.w;
            float wv = (j == 0) ? ww.x : (j == 1) ? ww.y : (j == 2) ? ww.z : ww.w;
            int b = dd / BDIV;
            int pos = atomicAdd(&lcur[b], 1);
            float2 xs = *(const float2*)(x + 2 * ss);
            vint4 r = {ss | ((dd - b * BDIV) << 17), __float_as_int(wv),
                       __float_as_int(xs.x), __float_as_int(xs.y)};
            staging[pos] = r;
        }
    }
}

// ---------- P3: per-bucket CSR finish, in-place via LDS segment buffer ----------
__global__ void __launch_bounds__(512) k_build(const int* __restrict__ bbase,
                                               const int* __restrict__ bcnt,
                                               vint4* __restrict__ staging,
                                               int* __restrict__ deg,
                                               int* __restrict__ rowst) {
    __shared__ vint4 seg[BCAP];       // 64 KB
    __shared__ int hist[256];
    __shared__ int lcur[BDIV];
    int b = blockIdx.x, tid = threadIdx.x;
    int base = bbase[b];
    int cnt = min(bcnt[b], BCAP);     // clamp is memory-safety only; never hit
    if (tid < 256) hist[tid] = 0;
    __syncthreads();
    for (int i = tid; i < cnt; i += 512) {
        vint4 r = staging[base + i];
        seg[i] = r;
        atomicAdd(&hist[r.x >> 17], 1);
    }
    __syncthreads();
    int v = (tid < 256) ? hist[tid] : 0;
    for (int off = 1; off < 256; off <<= 1) {   // inclusive scan (first 256 thr)
        int t = (tid < 256 && tid >= off) ? hist[tid - off] : 0;
        __syncthreads();
        if (tid < 256) hist[tid] += t;
        __syncthreads();
    }
    int n0 = b * BDIV;
    int nnode = min(BDIV, N_NODES - n0);
    if (tid < nnode) {
        deg[n0 + tid] = v;
        rowst[n0 + tid] = base + hist[tid] - v;
    }
    if (tid < BDIV) lcur[tid] = hist[tid] - v;  // exclusive prefix
    __syncthreads();
    for (int i = tid; i < cnt; i += 512) {
        vint4 r = seg[i];
        int pos = atomicAdd(&lcur[r.x >> 17], 1);
        staging[base + pos] = r;
    }
}

// ---------- P4: layer-1 gather, 8 lanes/node, zero random reads, fused MLP ----------
__global__ void __launch_bounds__(256) k_gather1(const int* __restrict__ deg,
                                                 const int* __restrict__ rowst,
                                                 const vint4* __restrict__ csr,
                                                 const float* __restrict__ x,
                                                 const float* __restrict__ consts,
                                                 const float* __restrict__ W1,
                                                 const float* __restrict__ b1,
                                                 const float* __restrict__ W2,
                                                 float* __restrict__ h2,
                                                 float* __restrict__ la) {
    __shared__ float w10[132], w11[132], b1s[132], w2s[132];  // stride-33 pad
    for (int j = threadIdx.x; j < 128; j += blockDim.x) {
        int jj = (j >> 5) * 33 + (j & 31);
        w10[jj] = W1[j];
        w11[jj] = W1[128 + j];
        b1s[jj] = b1[j];
        w2s[jj] = W2[j];
    }
    __syncthreads();
    int t = blockIdx.x * blockDim.x + threadIdx.x;
    int n = t >> 3, l = t & 7;
    if (n >= N_NODES) return;
    float c[20];
#pragma unroll
    for (int i = 0; i < 20; ++i) c[i] = consts[i];
    int rs = rowst[n], d = deg[n];
    float2 xn = *(const float2*)(x + 2 * n);
    float adv[4];
#pragma unroll
    for (int h = 0; h < 4; ++h) adv[h] = xn.x * c[8 + h] + xn.y * c[12 + h];
    float s[4] = {0, 0, 0, 0}, X0[4] = {0, 0, 0, 0}, X1[4] = {0, 0, 0, 0};
    float wsum = 0.f;
    for (int k = rs + l; k < rs + d; k += 8) {
        vint4 r = csr[k];
        float wt = __int_as_float(r.y);
        float x0s = __int_as_float(r.z), x1s = __int_as_float(r.w);
        wsum += wt;
#pragma unroll
        for (int h = 0; h < 4; ++h) {
            float as = x0s * c[h] + x1s * c[4 + h];
            float p = __expf(leaky(as + adv[h] + wt * c[16 + h]));
            s[h] += p;
            X0[h] += p * x0s;
            X1[h] += p * x1s;
        }
    }
#pragma unroll
    for (int off = 1; off < 8; off <<= 1) {
        wsum += __shfl_xor(wsum, off);
#pragma unroll
        for (int h = 0; h < 4; ++h) {
            s[h]  += __shfl_xor(s[h], off);
            X0[h] += __shfl_xor(X0[h], off);
            X1[h] += __shfl_xor(X1[h], off);
        }
    }
    // self loop (redundant on all 8 lanes): edge attr = mean incident weight
    float lav = wsum / fmaxf((float)d, 1.f);
#pragma unroll
    for (int h = 0; h < 4; ++h) {
        float aso = xn.x * c[h] + xn.y * c[4 + h];
        float p = __expf(leaky(aso + adv[h] + lav * c[16 + h]));
        s[h] += p;
        X0[h] += p * xn.x;
        X1[h] += p * xn.y;
    }
    // MLP tail: lane l -> head l&3, channel-half l>>2 (16 ch each)
    int hh = l & 3;
    float sh  = (hh == 0) ? s[0]  : (hh == 1) ? s[1]  : (hh == 2) ? s[2]  : s[3];
    float X0h = (hh == 0) ? X0[0] : (hh == 1) ? X0[1] : (hh == 2) ? X0[2] : X0[3];
    float X1h = (hh == 0) ? X1[0] : (hh == 1) ? X1[1] : (hh == 2) ? X1[2] : X1[3];
    float inv = 1.f / (sh + 1e-16f);
    X0h *= inv;
    X1h *= inv;
    float acc = 0.f;
    int basej = hh * 33 + (l >> 2) * 16;
    for (int cc = 0; cc < 16; ++cc) {
        float v = X0h * w10[basej + cc] + X1h * w11[basej + cc] + b1s[basej + cc];
        float el = v > 0.f ? v : __expf(v) - 1.f;  // elu
        acc += el * w2s[basej + cc];
    }
    acc += __shfl_xor(acc, 1);
    acc += __shfl_xor(acc, 2);
    acc += __shfl_xor(acc, 4);
    if (l == 0) {
        h2[n] = acc;
        la[n] = lav;
    }
}

// ---------- P5: layer-2 gather, 8 lanes/node -> out ----------
__global__ void __launch_bounds__(256) k_gather2(const int* __restrict__ deg,
                                                 const int* __restrict__ rowst,
                                                 const vint4* __restrict__ csr,
                                                 const float* __restrict__ h2,
                                                 const float* __restrict__ la,
                                                 const float* __restrict__ attS2,
                                                 const float* __restrict__ attD2,
                                                 const float* __restrict__ We2,
                                                 const float* __restrict__ attE2,
                                                 const float* __restrict__ b2,
                                                 float* __restrict__ out) {
    int t = blockIdx.x * blockDim.x + threadIdx.x;
    int n = t >> 3, l = t & 7;
    if (n >= N_NODES) return;
    float aS = attS2[0], aD = attD2[0], cE = We2[0] * attE2[0], bb = b2[0];
    int rs = rowst[n], d = deg[n];
    float hn = h2[n];
    float hnaD = hn * aD;
    float s = 0.f, acc = 0.f;
    for (int k = rs + l; k < rs + d; k += 8) {
        vint4 r = csr[k];
        float hs = h2[r.x & 0x1FFFF];
        float wt = __int_as_float(r.y);
        float p = __expf(leaky(hs * aS + hnaD + wt * cE));
        s += p;
        acc += p * hs;
    }
#pragma unroll
    for (int off = 1; off < 8; off <<= 1) {
        s   += __shfl_xor(s, off);
        acc += __shfl_xor(acc, off);
    }
    float p = __expf(leaky(hn * aS + hnaD + la[n] * cE));
    s += p;
    acc += p * hn;
    if (l == 0) out[n] = acc / (s + 1e-16f) + bb;
}

extern "C" void kernel_launch(void* const* d_in, const int* in_sizes, int n_in,
                              void* d_out, int out_size, void* d_ws, size_t ws_size,
                              hipStream_t stream) {
    const float* x     = (const float*)d_in[0];
    const int*   ei    = (const int*)d_in[1];
    const float* w     = (const float*)d_in[2];
    const float* W1    = (const float*)d_in[3];
    const float* attS1 = (const float*)d_in[4];
    const float* attD1 = (const float*)d_in[5];
    const float* We1   = (const float*)d_in[6];
    const float* attE1 = (const float*)d_in[7];
    const float* b1    = (const float*)d_in[8];
    const float* W2    = (const float*)d_in[9];
    const float* attS2 = (const float*)d_in[10];
    const float* attD2 = (const float*)d_in[11];
    const float* We2   = (const float*)d_in[12];
    const float* attE2 = (const float*)d_in[13];
    const float* b2    = (const float*)d_in[14];
    float* out = (float*)d_out;

    const size_t N = N_NODES;

    // workspace layout (~29.3 MB; nothing needs zero-init)
    int*   histT   = (int*)d_ws;                      // NBKT*PBS = 262144
    int*   offT    = histT + NBKT * PBS;              // NBKT*PBS = 262144 (bucket-major)
    int*   btot    = offT + NBKT * PBS;               // 512
    int*   bbase   = btot + NBKT;                     // 512
    int*   bcnt    = bbase + NBKT;                    // 512
    float* consts  = (float*)(bcnt + NBKT);           // 32
    vint4* staging = (vint4*)(consts + 32);           // E * 16B (16B-aligned)
    int*   deg     = (int*)(staging + N_EDGES);       // N
    int*   rowst   = deg + N;                         // N
    float* h2      = (float*)(rowst + N);             // N
    float* la      = h2 + N;                          // N

    k_hist<<<PB, 256, 0, stream>>>(ei, histT);
    k_rowscan<<<NBKT, 512, 0, stream>>>(histT, offT, btot);
    k_bprefix<<<1, 512, 0, stream>>>(btot, bbase, bcnt, W1, attS1, attD1, We1,
                                     attE1, consts);
    k_part<<<PB, 512, 0, stream>>>(ei, w, offT, bbase, x, staging);
    k_build<<<NUSED, 512, 0, stream>>>(bbase, bcnt, staging, deg, rowst);
    k_gather1<<<(8 * N_NODES + 255) / 256, 256, 0, stream>>>(deg, rowst, staging, x,
                                                             consts, W1, b1, W2, h2, la);
    k_gather2<<<(8 * N_NODES + 255) / 256, 256, 0, stream>>>(deg, rowst, staging, h2, la,
                                                             attS2, attD2, We2, attE2,
                                                             b2, out);
}